// Round 9
// baseline (227.298 us; speedup 1.0000x reference)
//
#include <hip/hip_runtime.h>
#include <hip/hip_bf16.h>

#define DEV __device__ __forceinline__

typedef __bf16 bf16;
typedef __bf16 bf16x4 __attribute__((ext_vector_type(4)));
typedef __bf16 bf16x8 __attribute__((ext_vector_type(8)));
typedef float f32x4 __attribute__((ext_vector_type(4)));

static constexpr int Bb = 4, Ll = 2048, Dd = 512, Ee = 8, Hh = 1024;
static constexpr int Mm = Bb * Ll;  // 8192 tokens
static constexpr int GKS = Ee * Hh; // 8192, G row stride

// ---------------- async global->LDS (16B per lane, wave-uniform LDS base) ---
DEV void gload_lds16(const void* g, void* l) {
  __builtin_amdgcn_global_load_lds(
      (const __attribute__((address_space(1))) unsigned int*)g,
      (__attribute__((address_space(3))) unsigned int*)l, 16, 0, 0);
}

// fast exact-enough gelu: tanh form, g = h - h/(exp(2y)+1)
DEV float gelu_fast(float h) {
  const float k = 0.7978845608028654f * 2.0f * 1.4426950408889634f;
  float h2 = h * h;
  float y = h * (k + (0.044715f * k) * h2);
  float t = exp2f(y);
  return h - h * __frcp_rn(t + 1.0f);
}

// ---------------- elementwise f32 -> bf16 -----------------------------------
__global__ void cvt_x_kernel(const float* __restrict__ in, bf16* __restrict__ out, int n4) {
  int i = blockIdx.x * blockDim.x + threadIdx.x;
  if (i < n4) {
    float4 v = ((const float4*)in)[i];
    bf16x4 o = {(bf16)v.x, (bf16)v.y, (bf16)v.z, (bf16)v.w};
    ((bf16x4*)out)[i] = o;
  }
}

// ---------------- tiled transpose + convert ---------------------------------
__global__ void transpose_cvt(const float* __restrict__ in, bf16* __restrict__ out,
                              int R, int C, size_t in_es, size_t out_es, int out_rs) {
  __shared__ float tile[64][65];
  const int e = blockIdx.z;
  const float* ip = in + (size_t)e * in_es;
  bf16* op = out + (size_t)e * out_es;
  const int r0 = blockIdx.y * 64, c0 = blockIdx.x * 64;
  const int tc = threadIdx.x & 63, tr = threadIdx.x >> 6;
#pragma unroll
  for (int i = 0; i < 16; ++i) {
    const int r = tr + i * 4;
    tile[r][tc] = ip[(size_t)(r0 + r) * C + c0 + tc];
  }
  __syncthreads();
  const int wr = threadIdx.x & 63, wc0 = threadIdx.x >> 6;
#pragma unroll
  for (int i = 0; i < 16; ++i) {
    const int c = wc0 + i * 4;
    op[(size_t)(c0 + c) * out_rs + r0 + wr] = (bf16)tile[wr][c];
  }
}

// ============ 256x128 GEMM core, BK=32, 48KB LDS, 2 blocks/CU ===============
// 8 waves (4M x 2N), wave output 64x64, acc[4][4] f32x4 = 64 VGPR.
// Rows are 64B = 4 segs of 16B; swizzle seg' = seg ^ (row&3) (uniform spread).
// 3 gloads/thread/K-tile (A 2 + B 1); counted vmcnt(3); 2 barriers/K-tile.
// MFMA operands swapped: acc[fi][fj][r]: m = wm*64+fi*16+(lane&15),
// n = wn*64+fj*16+(lane>>4)*4+r.
template <int ARS, int BRS>
DEV void gemm128_run(const bf16* __restrict__ Ag, const bf16* __restrict__ Bg,
                     int nt_k, f32x4 (&acc)[4][4], char* lds) {
  const int t = threadIdx.x;
  const int lane = t & 63;
  const int wid = t >> 6;
  const int wm = wid >> 1, wn = wid & 1;
  const int fr = lane & 15, fg = lane >> 4;
  const int srow = t >> 2;   // 0..127
  const int sseg = t & 3;    // 0..3

  auto stage = [&](int kt, int p) {
    char* As = lds + p * 24576;
    char* Bs = lds + p * 24576 + 16384;
#pragma unroll
    for (int i = 0; i < 2; ++i) {
      const int row = i * 128 + srow;
      const int q = sseg ^ (row & 3);
      gload_lds16(Ag + (size_t)row * ARS + kt * 32 + q * 8, As + i * 8192 + wid * 1024);
    }
    {
      const int row = srow;
      const int q = sseg ^ (row & 3);
      gload_lds16(Bg + (size_t)row * BRS + kt * 32 + q * 8, Bs + wid * 1024);
    }
  };

  stage(0, 0);
  for (int kt = 0; kt < nt_k; ++kt) {
    const int p = kt & 1;
    if (kt + 1 < nt_k) {
      stage(kt + 1, p ^ 1);
      asm volatile("s_waitcnt vmcnt(3)" ::: "memory");
    } else {
      asm volatile("s_waitcnt vmcnt(0)" ::: "memory");
    }
    __builtin_amdgcn_s_barrier();
    const char* As = lds + p * 24576;
    const char* Bs = lds + p * 24576 + 16384;
    bf16x8 bfr[4], af[4];
#pragma unroll
    for (int fj = 0; fj < 4; ++fj) {
      const int row = wn * 64 + fj * 16 + fr;
      const int s = fg ^ (row & 3);
      bfr[fj] = *(const bf16x8*)(Bs + row * 64 + s * 16);
    }
#pragma unroll
    for (int fi = 0; fi < 4; ++fi) {
      const int row = wm * 64 + fi * 16 + fr;
      const int s = fg ^ (row & 3);
      af[fi] = *(const bf16x8*)(As + row * 64 + s * 16);
    }
    __builtin_amdgcn_s_setprio(1);
#pragma unroll
    for (int fi = 0; fi < 4; ++fi)
#pragma unroll
      for (int fj = 0; fj < 4; ++fj)
        acc[fi][fj] = __builtin_amdgcn_mfma_f32_16x16x32_bf16(
            bfr[fj], af[fi], acc[fi][fj], 0, 0, 0);
    __builtin_amdgcn_s_setprio(0);
    __builtin_amdgcn_s_barrier();
  }
}

// ---------------- stage 1 (256x128): g = w[m,e]*gelu(x@W1_e + b1_e) ---------
__global__ __launch_bounds__(512, 4) void ffn_stage1_256(
    const bf16* __restrict__ xb, const bf16* __restrict__ w1t,
    const float* __restrict__ b1, const float* __restrict__ wts,
    bf16* __restrict__ G) {
  __shared__ __align__(16) char lds[49152];
  __shared__ float b1s[128];
  __shared__ float wls[256];
  const int mt = blockIdx.x, ct = blockIdx.y;  // ct: 128-col tile of E*H
  const int t = threadIdx.x;
  if (t < 128) b1s[t] = b1[ct * 128 + t];
  else if (t < 384) wls[t - 128] = wts[((size_t)mt * 256 + (t - 128)) * Ee + (ct >> 3)];

  f32x4 acc[4][4] = {};
  const bf16* Ag = xb + (size_t)mt * 256 * Dd;
  const bf16* Bg = w1t + (size_t)ct * 128 * Dd;
  gemm128_run<Dd, Dd>(Ag, Bg, Dd / 32, acc, lds);

  const int lane = t & 63, wid = t >> 6;
  const int wm = wid >> 1, wn = wid & 1;
  const int fr = lane & 15, fq = lane >> 4;
  float b1v[4][4];
#pragma unroll
  for (int fj = 0; fj < 4; ++fj)
#pragma unroll
    for (int r = 0; r < 4; ++r) b1v[fj][r] = b1s[wn * 64 + fj * 16 + fq * 4 + r];
#pragma unroll
  for (int fi = 0; fi < 4; ++fi) {
    const int m = mt * 256 + wm * 64 + fi * 16 + fr;
    const float wgt = wls[wm * 64 + fi * 16 + fr];
    bf16* gp = G + (size_t)m * GKS + ct * 128 + wn * 64 + fq * 4;
#pragma unroll
    for (int fj = 0; fj < 4; ++fj) {
      bf16x4 o;
#pragma unroll
      for (int r = 0; r < 4; ++r) {
        float v = acc[fi][fj][r] + b1v[fj][r];
        o[r] = (bf16)(gelu_fast(v) * wgt);
      }
      *(bf16x4*)(gp + fj * 16) = o;
    }
  }
}

// ---------------- stage 2 (256x128) split-K partial --------------------------
__global__ __launch_bounds__(512, 4) void ffn_stage2_256(
    const bf16* __restrict__ G, const bf16* __restrict__ w2t,
    float* __restrict__ P, int kchunk) {
  __shared__ __align__(16) char lds[49152];
  const int mt = blockIdx.x, nt = blockIdx.y, s = blockIdx.z;
  const int t = threadIdx.x;

  f32x4 acc[4][4] = {};
  const bf16* Ag = G + (size_t)mt * 256 * GKS + (size_t)s * kchunk;
  const bf16* Bg = w2t + (size_t)nt * 128 * GKS + (size_t)s * kchunk;
  gemm128_run<GKS, GKS>(Ag, Bg, kchunk / 32, acc, lds);

  float* Pp = P + (size_t)s * Mm * Dd;
  const int lane = t & 63, wid = t >> 6;
  const int wm = wid >> 1, wn = wid & 1;
  const int fr = lane & 15, fq = lane >> 4;
#pragma unroll
  for (int fi = 0; fi < 4; ++fi) {
    const size_t m = (size_t)mt * 256 + wm * 64 + fi * 16 + fr;
    float* pp = Pp + m * Dd + nt * 128 + wn * 64 + fq * 4;
#pragma unroll
    for (int fj = 0; fj < 4; ++fj) *(f32x4*)(pp + fj * 16) = acc[fi][fj];
  }
}

// ---------------- reduce partials + bias ------------------------------------
__global__ __launch_bounds__(256) void reduce_bias(
    const float* __restrict__ P, const float* __restrict__ wts,
    const float* __restrict__ b2, float* __restrict__ out, int S) {
  const int n4 = Mm * Dd / 4;
  int i = blockIdx.x * 256 + threadIdx.x;
  if (i >= n4) return;
  const int m = i / (Dd / 4);
  const int d0 = (i % (Dd / 4)) * 4;
  float4 a = ((const float4*)P)[i];
  for (int s = 1; s < S; ++s) {
    float4 p = ((const float4*)P)[(size_t)s * n4 + i];
    a.x += p.x; a.y += p.y; a.z += p.z; a.w += p.w;
  }
  const float* wr = wts + (size_t)m * Ee;
#pragma unroll
  for (int e = 0; e < Ee; ++e) {
    const float w = wr[e];
    float4 b = *(const float4*)(b2 + e * Dd + d0);
    a.x += w * b.x; a.y += w * b.y; a.z += w * b.z; a.w += w * b.w;
  }
  ((float4*)out)[i] = a;
}

// ============ fallback: 128^2 m97-structure path (R3 proven) ================
template <int ARS, int BRS>
DEV void gemm_core(const bf16* __restrict__ Ag, const bf16* __restrict__ Bg,
                   int ksteps, f32x4 (&acc)[4][4], bf16* As, bf16* Bs) {
  const int t = threadIdx.x;
  const int lane = t & 63;
  const int w = t >> 6;
  const int srow = t >> 3;
  const int sseg = t & 7;
  const int wr = w >> 1, wc = w & 1;
  const int fr = lane & 15;
  const int fg = lane >> 4;
  for (int s = 0; s < ksteps; ++s) {
    __syncthreads();
#pragma unroll
    for (int i = 0; i < 4; ++i) {
      const int row = i * 32 + srow;
      const int q = sseg ^ (row & 7);
      gload_lds16(Ag + (size_t)row * ARS + s * 64 + q * 8,
                  (char*)As + i * 4096 + w * 1024);
      gload_lds16(Bg + (size_t)row * BRS + s * 64 + q * 8,
                  (char*)Bs + i * 4096 + w * 1024);
    }
    __syncthreads();
#pragma unroll
    for (int kk = 0; kk < 2; ++kk) {
      bf16x8 af[4], bfr[4];
#pragma unroll
      for (int mi = 0; mi < 4; ++mi) {
        const int row = wr * 64 + mi * 16 + fr;
        const int q = (kk * 4 + fg) ^ (row & 7);
        af[mi] = *(const bf16x8*)((const char*)As + row * 128 + q * 16);
      }
#pragma unroll
      for (int ni = 0; ni < 4; ++ni) {
        const int row = wc * 64 + ni * 16 + fr;
        const int q = (kk * 4 + fg) ^ (row & 7);
        bfr[ni] = *(const bf16x8*)((const char*)Bs + row * 128 + q * 16);
      }
#pragma unroll
      for (int mi = 0; mi < 4; ++mi)
#pragma unroll
        for (int ni = 0; ni < 4; ++ni)
          acc[mi][ni] = __builtin_amdgcn_mfma_f32_16x16x32_bf16(
              af[mi], bfr[ni], acc[mi][ni], 0, 0, 0);
    }
  }
}

__global__ __launch_bounds__(256) void ffn_stage1_t(
    const bf16* __restrict__ xb, const bf16* __restrict__ w1t,
    const float* __restrict__ b1, const float* __restrict__ wts,
    bf16* __restrict__ G) {
  __shared__ __align__(16) bf16 As[128 * 64];
  __shared__ __align__(16) bf16 Bs[128 * 64];
  __shared__ float b1s[128];
  __shared__ float wls[128];
  const int mt = blockIdx.x, ht = blockIdx.y, e = blockIdx.z;
  const int t = threadIdx.x;
  if (t < 128) b1s[t] = b1[e * Hh + ht * 128 + t];
  else wls[t - 128] = wts[((size_t)mt * 128 + (t - 128)) * Ee + e];
  f32x4 acc[4][4] = {};
  const bf16* Ag = xb + (size_t)mt * 128 * Dd;
  const bf16* Bg = w1t + ((size_t)e * Hh + (size_t)ht * 128) * Dd;
  gemm_core<Dd, Dd>(Ag, Bg, Dd / 64, acc, As, Bs);
  const int lane = t & 63, w = t >> 6;
  const int wr = w >> 1, wc = w & 1, fr = lane & 15, fq = lane >> 4;
  float bcol[4];
#pragma unroll
  for (int ni = 0; ni < 4; ++ni) bcol[ni] = b1s[wc * 64 + ni * 16 + fr];
  bf16* gp = G + ((size_t)mt * 128 + wr * 64 + fq * 4) * GKS
               + (size_t)e * Hh + ht * 128 + wc * 64 + fr;
#pragma unroll
  for (int mi = 0; mi < 4; ++mi)
#pragma unroll
    for (int r = 0; r < 4; ++r) {
      const float wgt = wls[wr * 64 + mi * 16 + fq * 4 + r];
#pragma unroll
      for (int ni = 0; ni < 4; ++ni) {
        float v = acc[mi][ni][r] + bcol[ni];
        gp[(size_t)(mi * 16 + r) * GKS + ni * 16] = (bf16)(gelu_fast(v) * wgt);
      }
    }
}

__global__ __launch_bounds__(256) void ffn_stage2_partial(
    const bf16* __restrict__ G, const bf16* __restrict__ w2t,
    float* __restrict__ P, int kchunk) {
  __shared__ __align__(16) bf16 As[128 * 64];
  __shared__ __align__(16) bf16 Bs[128 * 64];
  const int mt = blockIdx.x, nt = blockIdx.y, s = blockIdx.z;
  f32x4 acc[4][4] = {};
  const bf16* Ag = G + (size_t)mt * 128 * GKS + (size_t)s * kchunk;
  const bf16* Bg = w2t + (size_t)nt * 128 * GKS + (size_t)s * kchunk;
  gemm_core<GKS, GKS>(Ag, Bg, kchunk / 64, acc, As, Bs);
  float* Pp = P + (size_t)s * Mm * Dd;
  const int t = threadIdx.x;
  const int lane = t & 63, w = t >> 6;
  const int wr = w >> 1, wc = w & 1, fr = lane & 15, fq = lane >> 4;
#pragma unroll
  for (int mi = 0; mi < 4; ++mi)
#pragma unroll
    for (int r = 0; r < 4; ++r) {
      const size_t m = (size_t)mt * 128 + wr * 64 + mi * 16 + fq * 4 + r;
#pragma unroll
      for (int ni = 0; ni < 4; ++ni) {
        const int d = nt * 128 + wc * 64 + ni * 16 + fr;
        Pp[m * Dd + d] = acc[mi][ni][r];
      }
    }
}

// ---------------- launch ----------------------------------------------------
extern "C" void kernel_launch(void* const* d_in, const int* in_sizes, int n_in,
                              void* d_out, int out_size, void* d_ws, size_t ws_size,
                              hipStream_t stream) {
  const float* x   = (const float*)d_in[0];
  const float* wts = (const float*)d_in[1];
  const float* w1  = (const float*)d_in[2];
  const float* b1  = (const float*)d_in[3];
  const float* w2  = (const float*)d_in[4];
  const float* b2  = (const float*)d_in[5];
  float* out = (float*)d_out;

  char* ws = (char*)d_ws;
  size_t off = 0;
  bf16* xb  = (bf16*)(ws + off); off += (size_t)Mm * Dd * 2;
  bf16* w1t = (bf16*)(ws + off); off += (size_t)Ee * Hh * Dd * 2;
  bf16* w2t = (bf16*)(ws + off); off += (size_t)Dd * Ee * Hh * 2;

  const size_t gfull = (size_t)Mm * Ee * Hh * 2;  // 134 MB
  const size_t psz   = (size_t)Mm * Dd * 4;       // 16.8 MB

  cvt_x_kernel<<<(Mm * Dd / 4 + 255) / 256, 256, 0, stream>>>(x, xb, Mm * Dd / 4);
  transpose_cvt<<<dim3(Hh / 64, Dd / 64, Ee), 256, 0, stream>>>(
      w1, w1t, Dd, Hh, (size_t)Dd * Hh, (size_t)Hh * Dd, Dd);
  transpose_cvt<<<dim3(Dd / 64, Hh / 64, Ee), 256, 0, stream>>>(
      w2, w2t, Hh, Dd, (size_t)Hh * Dd, (size_t)Hh, Ee * Hh);

  if (ws_size >= off + gfull + 4 * psz) {
    // main path: 256x128 BK=32 kernels at 2 blocks/CU, split-K S=4
    bf16* G = (bf16*)(ws + off);
    float* P = (float*)(ws + off + gfull);
    ffn_stage1_256<<<dim3(Mm / 256, GKS / 128), 512, 0, stream>>>(
        xb, w1t, b1, wts, G);
    ffn_stage2_256<<<dim3(Mm / 256, Dd / 128, 4), 512, 0, stream>>>(
        G, w2t, P, GKS / 4);
    reduce_bias<<<(Mm * Dd / 4 + 255) / 256, 256, 0, stream>>>(P, wts, b2, out, 4);
  } else if (ws_size >= off + gfull + 2 * psz) {
    // fallback: 128^2 split-K S=2 (R3 proven)
    bf16* G = (bf16*)(ws + off);
    float* P = (float*)(ws + off + gfull);
    ffn_stage1_t<<<dim3(Mm / 128, Hh / 128, Ee), 256, 0, stream>>>(
        xb, w1t, b1, wts, G);
    ffn_stage2_partial<<<dim3(Mm / 128, Dd / 128, 2), 256, 0, stream>>>(
        G, w2t, P, GKS / 2);
    reduce_bias<<<(Mm * Dd / 4 + 255) / 256, 256, 0, stream>>>(P, wts, b2, out, 2);
  }
}

// Round 10
// 226.825 us; speedup vs baseline: 1.0021x; 1.0021x over previous
//
#include <hip/hip_runtime.h>
#include <hip/hip_bf16.h>

#define DEV __device__ __forceinline__

typedef __bf16 bf16;
typedef __bf16 bf16x4 __attribute__((ext_vector_type(4)));
typedef __bf16 bf16x8 __attribute__((ext_vector_type(8)));
typedef float f32x4 __attribute__((ext_vector_type(4)));

static constexpr int Bb = 4, Ll = 2048, Dd = 512, Ee = 8, Hh = 1024;
static constexpr int Mm = Bb * Ll;  // 8192 tokens
static constexpr int GKS = Ee * Hh; // 8192, G row stride

// ---------------- async global->LDS (16B per lane, wave-uniform LDS base) ---
DEV void gload_lds16(const void* g, void* l) {
  __builtin_amdgcn_global_load_lds(
      (const __attribute__((address_space(1))) unsigned int*)g,
      (__attribute__((address_space(3))) unsigned int*)l, 16, 0, 0);
}

// fast exact-enough gelu: tanh form, g = h - h/(exp(2y)+1)
DEV float gelu_fast(float h) {
  const float k = 0.7978845608028654f * 2.0f * 1.4426950408889634f;
  float h2 = h * h;
  float y = h * (k + (0.044715f * k) * h2);
  float t = exp2f(y);
  return h - h * __frcp_rn(t + 1.0f);
}

// ---------------- elementwise f32 -> bf16 -----------------------------------
__global__ void cvt_x_kernel(const float* __restrict__ in, bf16* __restrict__ out, int n4) {
  int i = blockIdx.x * blockDim.x + threadIdx.x;
  if (i < n4) {
    float4 v = ((const float4*)in)[i];
    bf16x4 o = {(bf16)v.x, (bf16)v.y, (bf16)v.z, (bf16)v.w};
    ((bf16x4*)out)[i] = o;
  }
}

// ---------------- tiled transpose + convert ---------------------------------
__global__ void transpose_cvt(const float* __restrict__ in, bf16* __restrict__ out,
                              int R, int C, size_t in_es, size_t out_es, int out_rs) {
  __shared__ float tile[64][65];
  const int e = blockIdx.z;
  const float* ip = in + (size_t)e * in_es;
  bf16* op = out + (size_t)e * out_es;
  const int r0 = blockIdx.y * 64, c0 = blockIdx.x * 64;
  const int tc = threadIdx.x & 63, tr = threadIdx.x >> 6;
#pragma unroll
  for (int i = 0; i < 16; ++i) {
    const int r = tr + i * 4;
    tile[r][tc] = ip[(size_t)(r0 + r) * C + c0 + tc];
  }
  __syncthreads();
  const int wr = threadIdx.x & 63, wc0 = threadIdx.x >> 6;
#pragma unroll
  for (int i = 0; i < 16; ++i) {
    const int c = wc0 + i * 4;
    op[(size_t)(c0 + c) * out_rs + r0 + wr] = (bf16)tile[wr][c];
  }
}

// ============ 256x128 GEMM core, BK=32, triple-buffered, 2 blocks/CU ========
// 8 waves (4M x 2N), wave output 64x64, acc[4][4] f32x4 = 64 VGPR.
// LDS: 3 bufs x (A 16KB + B 8KB) = 72KB. Rows 64B = 4 segs of 16B.
// Swizzle key (row>>2)&3: bank-group = 4*(row&1) + seg' spans 8 values x2
// lanes over 16 rows -> 2-way aliasing = free (m136). Staging source seg
// sq = (t&3)^((t>>4)&3) (thread-constant); read slot rsl = fg^(fr>>2).
// Depth-2 prefetch: steady vmcnt(6) (2 stages x 3 loads in flight).
template <int ARS, int BRS>
DEV void gemm128_run(const bf16* __restrict__ Ag, const bf16* __restrict__ Bg,
                     int nt_k, f32x4 (&acc)[4][4], char* lds) {
  const int t = threadIdx.x;
  const int lane = t & 63;
  const int wid = t >> 6;
  const int wm = wid >> 1, wn = wid & 1;
  const int fr = lane & 15, fg = lane >> 4;
  const int srow = t >> 2;                  // 0..127
  const int sq = (t & 3) ^ ((t >> 4) & 3);  // pre-swizzled global seg
  const int rsl = fg ^ (fr >> 2);           // read slot seg

  auto stage = [&](int kt, int p) {
    char* As = lds + p * 24576;
    char* Bs = lds + p * 24576 + 16384;
#pragma unroll
    for (int i = 0; i < 2; ++i)
      gload_lds16(Ag + (size_t)(i * 128 + srow) * ARS + kt * 32 + sq * 8,
                  As + i * 8192 + wid * 1024);
    gload_lds16(Bg + (size_t)srow * BRS + kt * 32 + sq * 8, Bs + wid * 1024);
  };

  stage(0, 0);
  if (nt_k > 1) stage(1, 1);
  int cur = 0, stg = 2;
  for (int kt = 0; kt < nt_k; ++kt) {
    if (kt + 2 < nt_k) {
      stage(kt + 2, stg);
      asm volatile("s_waitcnt vmcnt(6)" ::: "memory");
    } else if (kt + 1 < nt_k) {
      asm volatile("s_waitcnt vmcnt(3)" ::: "memory");
    } else {
      asm volatile("s_waitcnt vmcnt(0)" ::: "memory");
    }
    __builtin_amdgcn_s_barrier();
    const char* As = lds + cur * 24576;
    const char* Bs = lds + cur * 24576 + 16384;
    bf16x8 bfr[4], af[4];
#pragma unroll
    for (int fj = 0; fj < 4; ++fj) {
      const int row = wn * 64 + fj * 16 + fr;
      bfr[fj] = *(const bf16x8*)(Bs + row * 64 + rsl * 16);
    }
#pragma unroll
    for (int fi = 0; fi < 4; ++fi) {
      const int row = wm * 64 + fi * 16 + fr;
      af[fi] = *(const bf16x8*)(As + row * 64 + rsl * 16);
    }
    __builtin_amdgcn_s_setprio(1);
#pragma unroll
    for (int fi = 0; fi < 4; ++fi)
#pragma unroll
      for (int fj = 0; fj < 4; ++fj)
        acc[fi][fj] = __builtin_amdgcn_mfma_f32_16x16x32_bf16(
            bfr[fj], af[fi], acc[fi][fj], 0, 0, 0);
    __builtin_amdgcn_s_setprio(0);
    __builtin_amdgcn_s_barrier();
    cur = cur == 2 ? 0 : cur + 1;
    stg = stg == 2 ? 0 : stg + 1;
  }
}

// ---------------- stage 1 (256x128): g = w[m,e]*gelu(x@W1_e + b1_e) ---------
__global__ __launch_bounds__(512, 4) void ffn_stage1_256(
    const bf16* __restrict__ xb, const bf16* __restrict__ w1t,
    const float* __restrict__ b1, const float* __restrict__ wts,
    bf16* __restrict__ G) {
  __shared__ __align__(16) char lds[73728];
  __shared__ float b1s[128];
  __shared__ float wls[256];
  const int mt = blockIdx.x, ct = blockIdx.y;  // ct: 128-col tile of E*H
  const int t = threadIdx.x;
  if (t < 128) b1s[t] = b1[ct * 128 + t];
  else if (t < 384) wls[t - 128] = wts[((size_t)mt * 256 + (t - 128)) * Ee + (ct >> 3)];

  f32x4 acc[4][4] = {};
  const bf16* Ag = xb + (size_t)mt * 256 * Dd;
  const bf16* Bg = w1t + (size_t)ct * 128 * Dd;
  gemm128_run<Dd, Dd>(Ag, Bg, Dd / 32, acc, lds);

  const int lane = t & 63, wid = t >> 6;
  const int wm = wid >> 1, wn = wid & 1;
  const int fr = lane & 15, fq = lane >> 4;
  float b1v[4][4];
#pragma unroll
  for (int fj = 0; fj < 4; ++fj)
#pragma unroll
    for (int r = 0; r < 4; ++r) b1v[fj][r] = b1s[wn * 64 + fj * 16 + fq * 4 + r];
#pragma unroll
  for (int fi = 0; fi < 4; ++fi) {
    const int m = mt * 256 + wm * 64 + fi * 16 + fr;
    const float wgt = wls[wm * 64 + fi * 16 + fr];
    bf16* gp = G + (size_t)m * GKS + ct * 128 + wn * 64 + fq * 4;
#pragma unroll
    for (int fj = 0; fj < 4; ++fj) {
      bf16x4 o;
#pragma unroll
      for (int r = 0; r < 4; ++r) {
        float v = acc[fi][fj][r] + b1v[fj][r];
        o[r] = (bf16)(gelu_fast(v) * wgt);
      }
      *(bf16x4*)(gp + fj * 16) = o;
    }
  }
}

// ---------------- stage 2 (256x128) split-K partial --------------------------
__global__ __launch_bounds__(512, 4) void ffn_stage2_256(
    const bf16* __restrict__ G, const bf16* __restrict__ w2t,
    float* __restrict__ P, int kchunk) {
  __shared__ __align__(16) char lds[73728];
  const int mt = blockIdx.x, nt = blockIdx.y, s = blockIdx.z;
  const int t = threadIdx.x;

  f32x4 acc[4][4] = {};
  const bf16* Ag = G + (size_t)mt * 256 * GKS + (size_t)s * kchunk;
  const bf16* Bg = w2t + (size_t)nt * 128 * GKS + (size_t)s * kchunk;
  gemm128_run<GKS, GKS>(Ag, Bg, kchunk / 32, acc, lds);

  float* Pp = P + (size_t)s * Mm * Dd;
  const int lane = t & 63, wid = t >> 6;
  const int wm = wid >> 1, wn = wid & 1;
  const int fr = lane & 15, fq = lane >> 4;
#pragma unroll
  for (int fi = 0; fi < 4; ++fi) {
    const size_t m = (size_t)mt * 256 + wm * 64 + fi * 16 + fr;
    float* pp = Pp + m * Dd + nt * 128 + wn * 64 + fq * 4;
#pragma unroll
    for (int fj = 0; fj < 4; ++fj) *(f32x4*)(pp + fj * 16) = acc[fi][fj];
  }
}

// ---------------- reduce partials + bias ------------------------------------
__global__ __launch_bounds__(256) void reduce_bias(
    const float* __restrict__ P, const float* __restrict__ wts,
    const float* __restrict__ b2, float* __restrict__ out, int S) {
  const int n4 = Mm * Dd / 4;
  int i = blockIdx.x * 256 + threadIdx.x;
  if (i >= n4) return;
  const int m = i / (Dd / 4);
  const int d0 = (i % (Dd / 4)) * 4;
  float4 a = ((const float4*)P)[i];
  for (int s = 1; s < S; ++s) {
    float4 p = ((const float4*)P)[(size_t)s * n4 + i];
    a.x += p.x; a.y += p.y; a.z += p.z; a.w += p.w;
  }
  const float* wr = wts + (size_t)m * Ee;
#pragma unroll
  for (int e = 0; e < Ee; ++e) {
    const float w = wr[e];
    float4 b = *(const float4*)(b2 + e * Dd + d0);
    a.x += w * b.x; a.y += w * b.y; a.z += w * b.z; a.w += w * b.w;
  }
  ((float4*)out)[i] = a;
}

// ============ fallback: 128^2 m97-structure path (R3 proven) ================
template <int ARS, int BRS>
DEV void gemm_core(const bf16* __restrict__ Ag, const bf16* __restrict__ Bg,
                   int ksteps, f32x4 (&acc)[4][4], bf16* As, bf16* Bs) {
  const int t = threadIdx.x;
  const int lane = t & 63;
  const int w = t >> 6;
  const int srow = t >> 3;
  const int sseg = t & 7;
  const int wr = w >> 1, wc = w & 1;
  const int fr = lane & 15;
  const int fg = lane >> 4;
  for (int s = 0; s < ksteps; ++s) {
    __syncthreads();
#pragma unroll
    for (int i = 0; i < 4; ++i) {
      const int row = i * 32 + srow;
      const int q = sseg ^ (row & 7);
      gload_lds16(Ag + (size_t)row * ARS + s * 64 + q * 8,
                  (char*)As + i * 4096 + w * 1024);
      gload_lds16(Bg + (size_t)row * BRS + s * 64 + q * 8,
                  (char*)Bs + i * 4096 + w * 1024);
    }
    __syncthreads();
#pragma unroll
    for (int kk = 0; kk < 2; ++kk) {
      bf16x8 af[4], bfr[4];
#pragma unroll
      for (int mi = 0; mi < 4; ++mi) {
        const int row = wr * 64 + mi * 16 + fr;
        const int q = (kk * 4 + fg) ^ (row & 7);
        af[mi] = *(const bf16x8*)((const char*)As + row * 128 + q * 16);
      }
#pragma unroll
      for (int ni = 0; ni < 4; ++ni) {
        const int row = wc * 64 + ni * 16 + fr;
        const int q = (kk * 4 + fg) ^ (row & 7);
        bfr[ni] = *(const bf16x8*)((const char*)Bs + row * 128 + q * 16);
      }
#pragma unroll
      for (int mi = 0; mi < 4; ++mi)
#pragma unroll
        for (int ni = 0; ni < 4; ++ni)
          acc[mi][ni] = __builtin_amdgcn_mfma_f32_16x16x32_bf16(
              af[mi], bfr[ni], acc[mi][ni], 0, 0, 0);
    }
  }
}

__global__ __launch_bounds__(256) void ffn_stage1_t(
    const bf16* __restrict__ xb, const bf16* __restrict__ w1t,
    const float* __restrict__ b1, const float* __restrict__ wts,
    bf16* __restrict__ G) {
  __shared__ __align__(16) bf16 As[128 * 64];
  __shared__ __align__(16) bf16 Bs[128 * 64];
  __shared__ float b1s[128];
  __shared__ float wls[128];
  const int mt = blockIdx.x, ht = blockIdx.y, e = blockIdx.z;
  const int t = threadIdx.x;
  if (t < 128) b1s[t] = b1[e * Hh + ht * 128 + t];
  else wls[t - 128] = wts[((size_t)mt * 128 + (t - 128)) * Ee + e];
  f32x4 acc[4][4] = {};
  const bf16* Ag = xb + (size_t)mt * 128 * Dd;
  const bf16* Bg = w1t + ((size_t)e * Hh + (size_t)ht * 128) * Dd;
  gemm_core<Dd, Dd>(Ag, Bg, Dd / 64, acc, As, Bs);
  const int lane = t & 63, w = t >> 6;
  const int wr = w >> 1, wc = w & 1, fr = lane & 15, fq = lane >> 4;
  float bcol[4];
#pragma unroll
  for (int ni = 0; ni < 4; ++ni) bcol[ni] = b1s[wc * 64 + ni * 16 + fr];
  bf16* gp = G + ((size_t)mt * 128 + wr * 64 + fq * 4) * GKS
               + (size_t)e * Hh + ht * 128 + wc * 64 + fr;
#pragma unroll
  for (int mi = 0; mi < 4; ++mi)
#pragma unroll
    for (int r = 0; r < 4; ++r) {
      const float wgt = wls[wr * 64 + mi * 16 + fq * 4 + r];
#pragma unroll
      for (int ni = 0; ni < 4; ++ni) {
        float v = acc[mi][ni][r] + bcol[ni];
        gp[(size_t)(mi * 16 + r) * GKS + ni * 16] = (bf16)(gelu_fast(v) * wgt);
      }
    }
}

__global__ __launch_bounds__(256) void ffn_stage2_partial(
    const bf16* __restrict__ G, const bf16* __restrict__ w2t,
    float* __restrict__ P, int kchunk) {
  __shared__ __align__(16) bf16 As[128 * 64];
  __shared__ __align__(16) bf16 Bs[128 * 64];
  const int mt = blockIdx.x, nt = blockIdx.y, s = blockIdx.z;
  f32x4 acc[4][4] = {};
  const bf16* Ag = G + (size_t)mt * 128 * GKS + (size_t)s * kchunk;
  const bf16* Bg = w2t + (size_t)nt * 128 * GKS + (size_t)s * kchunk;
  gemm_core<GKS, GKS>(Ag, Bg, kchunk / 64, acc, As, Bs);
  float* Pp = P + (size_t)s * Mm * Dd;
  const int t = threadIdx.x;
  const int lane = t & 63, w = t >> 6;
  const int wr = w >> 1, wc = w & 1, fr = lane & 15, fq = lane >> 4;
#pragma unroll
  for (int mi = 0; mi < 4; ++mi)
#pragma unroll
    for (int r = 0; r < 4; ++r) {
      const size_t m = (size_t)mt * 128 + wr * 64 + mi * 16 + fq * 4 + r;
#pragma unroll
      for (int ni = 0; ni < 4; ++ni) {
        const int d = nt * 128 + wc * 64 + ni * 16 + fr;
        Pp[m * Dd + d] = acc[mi][ni][r];
      }
    }
}

// ---------------- launch ----------------------------------------------------
extern "C" void kernel_launch(void* const* d_in, const int* in_sizes, int n_in,
                              void* d_out, int out_size, void* d_ws, size_t ws_size,
                              hipStream_t stream) {
  const float* x   = (const float*)d_in[0];
  const float* wts = (const float*)d_in[1];
  const float* w1  = (const float*)d_in[2];
  const float* b1  = (const float*)d_in[3];
  const float* w2  = (const float*)d_in[4];
  const float* b2  = (const float*)d_in[5];
  float* out = (float*)d_out;

  char* ws = (char*)d_ws;
  size_t off = 0;
  bf16* xb  = (bf16*)(ws + off); off += (size_t)Mm * Dd * 2;
  bf16* w1t = (bf16*)(ws + off); off += (size_t)Ee * Hh * Dd * 2;
  bf16* w2t = (bf16*)(ws + off); off += (size_t)Dd * Ee * Hh * 2;

  const size_t gfull = (size_t)Mm * Ee * Hh * 2;  // 134 MB
  const size_t psz   = (size_t)Mm * Dd * 4;       // 16.8 MB

  cvt_x_kernel<<<(Mm * Dd / 4 + 255) / 256, 256, 0, stream>>>(x, xb, Mm * Dd / 4);
  transpose_cvt<<<dim3(Hh / 64, Dd / 64, Ee), 256, 0, stream>>>(
      w1, w1t, Dd, Hh, (size_t)Dd * Hh, (size_t)Hh * Dd, Dd);
  transpose_cvt<<<dim3(Dd / 64, Hh / 64, Ee), 256, 0, stream>>>(
      w2, w2t, Hh, Dd, (size_t)Hh * Dd, (size_t)Hh, Ee * Hh);

  if (ws_size >= off + gfull + 4 * psz) {
    // main path: 256x128 BK=32 triple-buffered, conflict-free swizzle, S=4
    bf16* G = (bf16*)(ws + off);
    float* P = (float*)(ws + off + gfull);
    ffn_stage1_256<<<dim3(Mm / 256, GKS / 128), 512, 0, stream>>>(
        xb, w1t, b1, wts, G);
    ffn_stage2_256<<<dim3(Mm / 256, Dd / 128, 4), 512, 0, stream>>>(
        G, w2t, P, GKS / 4);
    reduce_bias<<<(Mm * Dd / 4 + 255) / 256, 256, 0, stream>>>(P, wts, b2, out, 4);
  } else if (ws_size >= off + gfull + 2 * psz) {
    // fallback: 128^2 split-K S=2 (R3 proven)
    bf16* G = (bf16*)(ws + off);
    float* P = (float*)(ws + off + gfull);
    ffn_stage1_t<<<dim3(Mm / 128, Hh / 128, Ee), 256, 0, stream>>>(
        xb, w1t, b1, wts, G);
    ffn_stage2_partial<<<dim3(Mm / 128, Dd / 128, 2), 256, 0, stream>>>(
        G, w2t, P, GKS / 2);
    reduce_bias<<<(Mm * Dd / 4 + 255) / 256, 256, 0, stream>>>(P, wts, b2, out, 2);
  }
}

// Round 11
// 225.522 us; speedup vs baseline: 1.0079x; 1.0058x over previous
//
#include <hip/hip_runtime.h>
#include <hip/hip_bf16.h>

#define DEV __device__ __forceinline__

typedef __bf16 bf16;
typedef __bf16 bf16x4 __attribute__((ext_vector_type(4)));
typedef __bf16 bf16x8 __attribute__((ext_vector_type(8)));
typedef float f32x4 __attribute__((ext_vector_type(4)));

static constexpr int Bb = 4, Ll = 2048, Dd = 512, Ee = 8, Hh = 1024;
static constexpr int Mm = Bb * Ll;  // 8192 tokens
static constexpr int GKS = Ee * Hh; // 8192, G row stride

// ---------------- async global->LDS (16B per lane, wave-uniform LDS base) ---
DEV void gload_lds16(const void* g, void* l) {
  __builtin_amdgcn_global_load_lds(
      (const __attribute__((address_space(1))) unsigned int*)g,
      (__attribute__((address_space(3))) unsigned int*)l, 16, 0, 0);
}

// fast exact-enough gelu: tanh form, g = h - h/(exp(2y)+1)
DEV float gelu_fast(float h) {
  const float k = 0.7978845608028654f * 2.0f * 1.4426950408889634f;
  float h2 = h * h;
  float y = h * (k + (0.044715f * k) * h2);
  float t = exp2f(y);
  return h - h * __frcp_rn(t + 1.0f);
}

// ---------------- elementwise f32 -> bf16 -----------------------------------
__global__ void cvt_x_kernel(const float* __restrict__ in, bf16* __restrict__ out, int n4) {
  int i = blockIdx.x * blockDim.x + threadIdx.x;
  if (i < n4) {
    float4 v = ((const float4*)in)[i];
    bf16x4 o = {(bf16)v.x, (bf16)v.y, (bf16)v.z, (bf16)v.w};
    ((bf16x4*)out)[i] = o;
  }
}

// ---------------- tiled transpose + convert ---------------------------------
__global__ void transpose_cvt(const float* __restrict__ in, bf16* __restrict__ out,
                              int R, int C, size_t in_es, size_t out_es, int out_rs) {
  __shared__ float tile[64][65];
  const int e = blockIdx.z;
  const float* ip = in + (size_t)e * in_es;
  bf16* op = out + (size_t)e * out_es;
  const int r0 = blockIdx.y * 64, c0 = blockIdx.x * 64;
  const int tc = threadIdx.x & 63, tr = threadIdx.x >> 6;
#pragma unroll
  for (int i = 0; i < 16; ++i) {
    const int r = tr + i * 4;
    tile[r][tc] = ip[(size_t)(r0 + r) * C + c0 + tc];
  }
  __syncthreads();
  const int wr = threadIdx.x & 63, wc0 = threadIdx.x >> 6;
#pragma unroll
  for (int i = 0; i < 16; ++i) {
    const int c = wc0 + i * 4;
    op[(size_t)(c0 + c) * out_rs + r0 + wr] = (bf16)tile[wr][c];
  }
}

// ============ 256x128 GEMM core, BK=32, triple-buffered, 2 blocks/CU ========
// 8 waves (4M x 2N), wave output 64x64, acc[4][4] f32x4 = 64 VGPR.
// LDS: 3 bufs x (A 16KB + B 8KB) = 72KB. Rows 64B = 4 segs of 16B.
// b128 reads are processed in 8-lane phases (8x16B = one 32-bank row).
// Bank-group of a read = 4*(row&1) + swz; with swizzle KEY = (row>>1)&3 the
// 8 lanes of a phase (fr=r0..r0+7) cover all 8 four-bank groups:
// (fr&1, fg^((fr>>1)&3)) is a bijection onto {0,1}x{0..3}. R9's (row&3) and
// R10's ((row>>2)&3) keys both collapsed to 4 groups -> 2-way -> 8.4M
// conflicts; this key is conflict-free.
// Staging source seg sq = (t&3)^((t>>3)&3) (thread-constant; dest row = t>>2,
// key(row) = (t>>3)&3). Read slot rsl = fg^((fr>>1)&3) (row bases are =0 mod 8).
// Depth-2 prefetch: steady vmcnt(6) (2 stages x 3 loads in flight).
template <int ARS, int BRS>
DEV void gemm128_run(const bf16* __restrict__ Ag, const bf16* __restrict__ Bg,
                     int nt_k, f32x4 (&acc)[4][4], char* lds) {
  const int t = threadIdx.x;
  const int lane = t & 63;
  const int wid = t >> 6;
  const int wm = wid >> 1, wn = wid & 1;
  const int fr = lane & 15, fg = lane >> 4;
  const int srow = t >> 2;                  // 0..127
  const int sq = (t & 3) ^ ((t >> 3) & 3);  // pre-swizzled global seg
  const int rsl = fg ^ ((fr >> 1) & 3);     // read slot seg

  auto stage = [&](int kt, int p) {
    char* As = lds + p * 24576;
    char* Bs = lds + p * 24576 + 16384;
#pragma unroll
    for (int i = 0; i < 2; ++i)
      gload_lds16(Ag + (size_t)(i * 128 + srow) * ARS + kt * 32 + sq * 8,
                  As + i * 8192 + wid * 1024);
    gload_lds16(Bg + (size_t)srow * BRS + kt * 32 + sq * 8, Bs + wid * 1024);
  };

  stage(0, 0);
  if (nt_k > 1) stage(1, 1);
  int cur = 0, stg = 2;
  for (int kt = 0; kt < nt_k; ++kt) {
    if (kt + 2 < nt_k) {
      stage(kt + 2, stg);
      asm volatile("s_waitcnt vmcnt(6)" ::: "memory");
    } else if (kt + 1 < nt_k) {
      asm volatile("s_waitcnt vmcnt(3)" ::: "memory");
    } else {
      asm volatile("s_waitcnt vmcnt(0)" ::: "memory");
    }
    __builtin_amdgcn_s_barrier();
    const char* As = lds + cur * 24576;
    const char* Bs = lds + cur * 24576 + 16384;
    bf16x8 bfr[4], af[4];
#pragma unroll
    for (int fj = 0; fj < 4; ++fj) {
      const int row = wn * 64 + fj * 16 + fr;
      bfr[fj] = *(const bf16x8*)(Bs + row * 64 + rsl * 16);
    }
#pragma unroll
    for (int fi = 0; fi < 4; ++fi) {
      const int row = wm * 64 + fi * 16 + fr;
      af[fi] = *(const bf16x8*)(As + row * 64 + rsl * 16);
    }
    __builtin_amdgcn_s_setprio(1);
#pragma unroll
    for (int fi = 0; fi < 4; ++fi)
#pragma unroll
      for (int fj = 0; fj < 4; ++fj)
        acc[fi][fj] = __builtin_amdgcn_mfma_f32_16x16x32_bf16(
            bfr[fj], af[fi], acc[fi][fj], 0, 0, 0);
    __builtin_amdgcn_s_setprio(0);
    __builtin_amdgcn_s_barrier();
    cur = cur == 2 ? 0 : cur + 1;
    stg = stg == 2 ? 0 : stg + 1;
  }
}

// ---------------- stage 1 (256x128): g = w[m,e]*gelu(x@W1_e + b1_e) ---------
__global__ __launch_bounds__(512, 4) void ffn_stage1_256(
    const bf16* __restrict__ xb, const bf16* __restrict__ w1t,
    const float* __restrict__ b1, const float* __restrict__ wts,
    bf16* __restrict__ G) {
  __shared__ __align__(16) char lds[73728];
  __shared__ float b1s[128];
  __shared__ float wls[256];
  const int mt = blockIdx.x, ct = blockIdx.y;  // ct: 128-col tile of E*H
  const int t = threadIdx.x;
  if (t < 128) b1s[t] = b1[ct * 128 + t];
  else if (t < 384) wls[t - 128] = wts[((size_t)mt * 256 + (t - 128)) * Ee + (ct >> 3)];

  f32x4 acc[4][4] = {};
  const bf16* Ag = xb + (size_t)mt * 256 * Dd;
  const bf16* Bg = w1t + (size_t)ct * 128 * Dd;
  gemm128_run<Dd, Dd>(Ag, Bg, Dd / 32, acc, lds);

  const int lane = t & 63, wid = t >> 6;
  const int wm = wid >> 1, wn = wid & 1;
  const int fr = lane & 15, fq = lane >> 4;
  float b1v[4][4];
#pragma unroll
  for (int fj = 0; fj < 4; ++fj)
#pragma unroll
    for (int r = 0; r < 4; ++r) b1v[fj][r] = b1s[wn * 64 + fj * 16 + fq * 4 + r];
#pragma unroll
  for (int fi = 0; fi < 4; ++fi) {
    const int m = mt * 256 + wm * 64 + fi * 16 + fr;
    const float wgt = wls[wm * 64 + fi * 16 + fr];
    bf16* gp = G + (size_t)m * GKS + ct * 128 + wn * 64 + fq * 4;
#pragma unroll
    for (int fj = 0; fj < 4; ++fj) {
      bf16x4 o;
#pragma unroll
      for (int r = 0; r < 4; ++r) {
        float v = acc[fi][fj][r] + b1v[fj][r];
        o[r] = (bf16)(gelu_fast(v) * wgt);
      }
      *(bf16x4*)(gp + fj * 16) = o;
    }
  }
}

// ---------------- stage 2 (256x128) split-K partial --------------------------
__global__ __launch_bounds__(512, 4) void ffn_stage2_256(
    const bf16* __restrict__ G, const bf16* __restrict__ w2t,
    float* __restrict__ P, int kchunk) {
  __shared__ __align__(16) char lds[73728];
  const int mt = blockIdx.x, nt = blockIdx.y, s = blockIdx.z;
  const int t = threadIdx.x;

  f32x4 acc[4][4] = {};
  const bf16* Ag = G + (size_t)mt * 256 * GKS + (size_t)s * kchunk;
  const bf16* Bg = w2t + (size_t)nt * 128 * GKS + (size_t)s * kchunk;
  gemm128_run<GKS, GKS>(Ag, Bg, kchunk / 32, acc, lds);

  float* Pp = P + (size_t)s * Mm * Dd;
  const int lane = t & 63, wid = t >> 6;
  const int wm = wid >> 1, wn = wid & 1;
  const int fr = lane & 15, fq = lane >> 4;
#pragma unroll
  for (int fi = 0; fi < 4; ++fi) {
    const size_t m = (size_t)mt * 256 + wm * 64 + fi * 16 + fr;
    float* pp = Pp + m * Dd + nt * 128 + wn * 64 + fq * 4;
#pragma unroll
    for (int fj = 0; fj < 4; ++fj) *(f32x4*)(pp + fj * 16) = acc[fi][fj];
  }
}

// ---------------- reduce partials + bias ------------------------------------
__global__ __launch_bounds__(256) void reduce_bias(
    const float* __restrict__ P, const float* __restrict__ wts,
    const float* __restrict__ b2, float* __restrict__ out, int S) {
  const int n4 = Mm * Dd / 4;
  int i = blockIdx.x * 256 + threadIdx.x;
  if (i >= n4) return;
  const int m = i / (Dd / 4);
  const int d0 = (i % (Dd / 4)) * 4;
  float4 a = ((const float4*)P)[i];
  for (int s = 1; s < S; ++s) {
    float4 p = ((const float4*)P)[(size_t)s * n4 + i];
    a.x += p.x; a.y += p.y; a.z += p.z; a.w += p.w;
  }
  const float* wr = wts + (size_t)m * Ee;
#pragma unroll
  for (int e = 0; e < Ee; ++e) {
    const float w = wr[e];
    float4 b = *(const float4*)(b2 + e * Dd + d0);
    a.x += w * b.x; a.y += w * b.y; a.z += w * b.z; a.w += w * b.w;
  }
  ((float4*)out)[i] = a;
}

// ============ fallback: 128^2 m97-structure path (R3 proven) ================
template <int ARS, int BRS>
DEV void gemm_core(const bf16* __restrict__ Ag, const bf16* __restrict__ Bg,
                   int ksteps, f32x4 (&acc)[4][4], bf16* As, bf16* Bs) {
  const int t = threadIdx.x;
  const int lane = t & 63;
  const int w = t >> 6;
  const int srow = t >> 3;
  const int sseg = t & 7;
  const int wr = w >> 1, wc = w & 1;
  const int fr = lane & 15;
  const int fg = lane >> 4;
  for (int s = 0; s < ksteps; ++s) {
    __syncthreads();
#pragma unroll
    for (int i = 0; i < 4; ++i) {
      const int row = i * 32 + srow;
      const int q = sseg ^ (row & 7);
      gload_lds16(Ag + (size_t)row * ARS + s * 64 + q * 8,
                  (char*)As + i * 4096 + w * 1024);
      gload_lds16(Bg + (size_t)row * BRS + s * 64 + q * 8,
                  (char*)Bs + i * 4096 + w * 1024);
    }
    __syncthreads();
#pragma unroll
    for (int kk = 0; kk < 2; ++kk) {
      bf16x8 af[4], bfr[4];
#pragma unroll
      for (int mi = 0; mi < 4; ++mi) {
        const int row = wr * 64 + mi * 16 + fr;
        const int q = (kk * 4 + fg) ^ (row & 7);
        af[mi] = *(const bf16x8*)((const char*)As + row * 128 + q * 16);
      }
#pragma unroll
      for (int ni = 0; ni < 4; ++ni) {
        const int row = wc * 64 + ni * 16 + fr;
        const int q = (kk * 4 + fg) ^ (row & 7);
        bfr[ni] = *(const bf16x8*)((const char*)Bs + row * 128 + q * 16);
      }
#pragma unroll
      for (int mi = 0; mi < 4; ++mi)
#pragma unroll
        for (int ni = 0; ni < 4; ++ni)
          acc[mi][ni] = __builtin_amdgcn_mfma_f32_16x16x32_bf16(
              af[mi], bfr[ni], acc[mi][ni], 0, 0, 0);
    }
  }
}

__global__ __launch_bounds__(256) void ffn_stage1_t(
    const bf16* __restrict__ xb, const bf16* __restrict__ w1t,
    const float* __restrict__ b1, const float* __restrict__ wts,
    bf16* __restrict__ G) {
  __shared__ __align__(16) bf16 As[128 * 64];
  __shared__ __align__(16) bf16 Bs[128 * 64];
  __shared__ float b1s[128];
  __shared__ float wls[128];
  const int mt = blockIdx.x, ht = blockIdx.y, e = blockIdx.z;
  const int t = threadIdx.x;
  if (t < 128) b1s[t] = b1[e * Hh + ht * 128 + t];
  else wls[t - 128] = wts[((size_t)mt * 128 + (t - 128)) * Ee + e];
  f32x4 acc[4][4] = {};
  const bf16* Ag = xb + (size_t)mt * 128 * Dd;
  const bf16* Bg = w1t + ((size_t)e * Hh + (size_t)ht * 128) * Dd;
  gemm_core<Dd, Dd>(Ag, Bg, Dd / 64, acc, As, Bs);
  const int lane = t & 63, w = t >> 6;
  const int wr = w >> 1, wc = w & 1, fr = lane & 15, fq = lane >> 4;
  float bcol[4];
#pragma unroll
  for (int ni = 0; ni < 4; ++ni) bcol[ni] = b1s[wc * 64 + ni * 16 + fr];
  bf16* gp = G + ((size_t)mt * 128 + wr * 64 + fq * 4) * GKS
               + (size_t)e * Hh + ht * 128 + wc * 64 + fr;
#pragma unroll
  for (int mi = 0; mi < 4; ++mi)
#pragma unroll
    for (int r = 0; r < 4; ++r) {
      const float wgt = wls[wr * 64 + mi * 16 + fq * 4 + r];
#pragma unroll
      for (int ni = 0; ni < 4; ++ni) {
        float v = acc[mi][ni][r] + bcol[ni];
        gp[(size_t)(mi * 16 + r) * GKS + ni * 16] = (bf16)(gelu_fast(v) * wgt);
      }
    }
}

__global__ __launch_bounds__(256) void ffn_stage2_partial(
    const bf16* __restrict__ G, const bf16* __restrict__ w2t,
    float* __restrict__ P, int kchunk) {
  __shared__ __align__(16) bf16 As[128 * 64];
  __shared__ __align__(16) bf16 Bs[128 * 64];
  const int mt = blockIdx.x, nt = blockIdx.y, s = blockIdx.z;
  f32x4 acc[4][4] = {};
  const bf16* Ag = G + (size_t)mt * 128 * GKS + (size_t)s * kchunk;
  const bf16* Bg = w2t + (size_t)nt * 128 * GKS + (size_t)s * kchunk;
  gemm_core<GKS, GKS>(Ag, Bg, kchunk / 64, acc, As, Bs);
  float* Pp = P + (size_t)s * Mm * Dd;
  const int t = threadIdx.x;
  const int lane = t & 63, w = t >> 6;
  const int wr = w >> 1, wc = w & 1, fr = lane & 15, fq = lane >> 4;
#pragma unroll
  for (int mi = 0; mi < 4; ++mi)
#pragma unroll
    for (int r = 0; r < 4; ++r) {
      const size_t m = (size_t)mt * 128 + wr * 64 + mi * 16 + fq * 4 + r;
#pragma unroll
      for (int ni = 0; ni < 4; ++ni) {
        const int d = nt * 128 + wc * 64 + ni * 16 + fr;
        Pp[m * Dd + d] = acc[mi][ni][r];
      }
    }
}

// ---------------- launch ----------------------------------------------------
extern "C" void kernel_launch(void* const* d_in, const int* in_sizes, int n_in,
                              void* d_out, int out_size, void* d_ws, size_t ws_size,
                              hipStream_t stream) {
  const float* x   = (const float*)d_in[0];
  const float* wts = (const float*)d_in[1];
  const float* w1  = (const float*)d_in[2];
  const float* b1  = (const float*)d_in[3];
  const float* w2  = (const float*)d_in[4];
  const float* b2  = (const float*)d_in[5];
  float* out = (float*)d_out;

  char* ws = (char*)d_ws;
  size_t off = 0;
  bf16* xb  = (bf16*)(ws + off); off += (size_t)Mm * Dd * 2;
  bf16* w1t = (bf16*)(ws + off); off += (size_t)Ee * Hh * Dd * 2;
  bf16* w2t = (bf16*)(ws + off); off += (size_t)Dd * Ee * Hh * 2;

  const size_t gfull = (size_t)Mm * Ee * Hh * 2;  // 134 MB
  const size_t psz   = (size_t)Mm * Dd * 4;       // 16.8 MB

  cvt_x_kernel<<<(Mm * Dd / 4 + 255) / 256, 256, 0, stream>>>(x, xb, Mm * Dd / 4);
  transpose_cvt<<<dim3(Hh / 64, Dd / 64, Ee), 256, 0, stream>>>(
      w1, w1t, Dd, Hh, (size_t)Dd * Hh, (size_t)Hh * Dd, Dd);
  transpose_cvt<<<dim3(Dd / 64, Hh / 64, Ee), 256, 0, stream>>>(
      w2, w2t, Hh, Dd, (size_t)Hh * Dd, (size_t)Hh, Ee * Hh);

  if (ws_size >= off + gfull + 4 * psz) {
    // main path: 256x128 BK=32 triple-buffered, phase-correct swizzle, S=4
    bf16* G = (bf16*)(ws + off);
    float* P = (float*)(ws + off + gfull);
    ffn_stage1_256<<<dim3(Mm / 256, GKS / 128), 512, 0, stream>>>(
        xb, w1t, b1, wts, G);
    ffn_stage2_256<<<dim3(Mm / 256, Dd / 128, 4), 512, 0, stream>>>(
        G, w2t, P, GKS / 4);
    reduce_bias<<<(Mm * Dd / 4 + 255) / 256, 256, 0, stream>>>(P, wts, b2, out, 4);
  } else if (ws_size >= off + gfull + 2 * psz) {
    // fallback: 128^2 split-K S=2 (R3 proven)
    bf16* G = (bf16*)(ws + off);
    float* P = (float*)(ws + off + gfull);
    ffn_stage1_t<<<dim3(Mm / 128, Hh / 128, Ee), 256, 0, stream>>>(
        xb, w1t, b1, wts, G);
    ffn_stage2_partial<<<dim3(Mm / 128, Dd / 128, 2), 256, 0, stream>>>(
        G, w2t, P, GKS / 2);
    reduce_bias<<<(Mm * Dd / 4 + 255) / 256, 256, 0, stream>>>(P, wts, b2, out, 2);
  }
}

// Round 12
// 223.903 us; speedup vs baseline: 1.0152x; 1.0072x over previous
//
#include <hip/hip_runtime.h>
#include <hip/hip_bf16.h>

#define DEV __device__ __forceinline__

typedef __bf16 bf16;
typedef __bf16 bf16x4 __attribute__((ext_vector_type(4)));
typedef __bf16 bf16x8 __attribute__((ext_vector_type(8)));
typedef float f32x4 __attribute__((ext_vector_type(4)));

static constexpr int Bb = 4, Ll = 2048, Dd = 512, Ee = 8, Hh = 1024;
static constexpr int Mm = Bb * Ll;  // 8192 tokens
static constexpr int GKS = Ee * Hh; // 8192, G row stride

// ---------------- async global->LDS (16B per lane, wave-uniform LDS base) ---
DEV void gload_lds16(const void* g, void* l) {
  __builtin_amdgcn_global_load_lds(
      (const __attribute__((address_space(1))) unsigned int*)g,
      (__attribute__((address_space(3))) unsigned int*)l, 16, 0, 0);
}

// fast exact-enough gelu: tanh form, g = h - h/(exp(2y)+1)
DEV float gelu_fast(float h) {
  const float k = 0.7978845608028654f * 2.0f * 1.4426950408889634f;
  float h2 = h * h;
  float y = h * (k + (0.044715f * k) * h2);
  float t = exp2f(y);
  return h - h * __frcp_rn(t + 1.0f);
}

// ---------------- elementwise f32 -> bf16 -----------------------------------
__global__ void cvt_x_kernel(const float* __restrict__ in, bf16* __restrict__ out, int n4) {
  int i = blockIdx.x * blockDim.x + threadIdx.x;
  if (i < n4) {
    float4 v = ((const float4*)in)[i];
    bf16x4 o = {(bf16)v.x, (bf16)v.y, (bf16)v.z, (bf16)v.w};
    ((bf16x4*)out)[i] = o;
  }
}

// ---------------- tiled transpose + convert ---------------------------------
__global__ void transpose_cvt(const float* __restrict__ in, bf16* __restrict__ out,
                              int R, int C, size_t in_es, size_t out_es, int out_rs) {
  __shared__ float tile[64][65];
  const int e = blockIdx.z;
  const float* ip = in + (size_t)e * in_es;
  bf16* op = out + (size_t)e * out_es;
  const int r0 = blockIdx.y * 64, c0 = blockIdx.x * 64;
  const int tc = threadIdx.x & 63, tr = threadIdx.x >> 6;
#pragma unroll
  for (int i = 0; i < 16; ++i) {
    const int r = tr + i * 4;
    tile[r][tc] = ip[(size_t)(r0 + r) * C + c0 + tc];
  }
  __syncthreads();
  const int wr = threadIdx.x & 63, wc0 = threadIdx.x >> 6;
#pragma unroll
  for (int i = 0; i < 16; ++i) {
    const int c = wc0 + i * 4;
    op[(size_t)(c0 + c) * out_rs + r0 + wr] = (bf16)tile[wr][c];
  }
}

// ============ 256x256, BK=32, triple-buffered fine-interleave core ==========
// 512 thr = 8 waves (2M x 4N), wave tile 128x64, acc[8][4] f32x4 = 128 VGPR.
// LDS: 3 bufs x (A 16KB + B 16KB) = 96KB. 64B rows, R11-verified swizzle:
// sq=(t&3)^((t>>3)&3) staging, rsl=fg^((fr>>1)&3) reads -> 0 conflicts.
// Per K-tile 2 phases: {ds_reads + 2 gloads(kt+2) + bar + lgkm0 + prio1 +
// 16 MFMA + prio0}; boundary {vmcnt(4) + bar} -- counted, never drains.
// Triple buffer makes stage-2-ahead WAR-safe: buf[(it+2)%3] was consumed
// at it-1, and gload issue is after it-1's trailing barriers.
#define PIPE_DECLS                                                   \
  const int t = threadIdx.x;                                         \
  const int lane = t & 63;                                           \
  const int wid = t >> 6;                                            \
  const int wm = wid >> 2, wn = wid & 3;                             \
  const int fr = lane & 15, fg = lane >> 4, fq = lane >> 4;          \
  const int srow = t >> 2;                                           \
  const int sq = (t & 3) ^ ((t >> 3) & 3);                           \
  const int rsl = fg ^ ((fr >> 1) & 3);

#define PHASE0(buf)                                                  \
  bf16x8 bfr[4], af[4];                                              \
  _Pragma("unroll") for (int fj = 0; fj < 4; ++fj) {                 \
    const int row = wn * 64 + fj * 16 + fr;                          \
    bfr[fj] = *(const bf16x8*)((buf) + 16384 + row * 64 + rsl * 16); \
  }                                                                  \
  _Pragma("unroll") for (int fi = 0; fi < 4; ++fi) {                 \
    const int row = wm * 128 + fi * 16 + fr;                         \
    af[fi] = *(const bf16x8*)((buf) + row * 64 + rsl * 16);          \
  }

#define PHASE1_READS(buf)                                            \
  bf16x8 af2[4];                                                     \
  _Pragma("unroll") for (int fi = 0; fi < 4; ++fi) {                 \
    const int row = wm * 128 + (4 + fi) * 16 + fr;                   \
    af2[fi] = *(const bf16x8*)((buf) + row * 64 + rsl * 16);         \
  }

#define MFMA_CLUSTER(A, ACCOFF)                                      \
  __builtin_amdgcn_s_barrier();                                      \
  asm volatile("s_waitcnt lgkmcnt(0)" ::: "memory");                 \
  __builtin_amdgcn_sched_barrier(0);                                 \
  __builtin_amdgcn_s_setprio(1);                                     \
  _Pragma("unroll") for (int fi = 0; fi < 4; ++fi)                   \
  _Pragma("unroll") for (int fj = 0; fj < 4; ++fj)                   \
    acc[(ACCOFF) + fi][fj] = __builtin_amdgcn_mfma_f32_16x16x32_bf16(\
        bfr[fj], (A)[fi], acc[(ACCOFF) + fi][fj], 0, 0, 0);          \
  __builtin_amdgcn_s_setprio(0);

// ---------------- stage 1: persistent over ct, fine-interleaved -------------
// Grid (32 mt, 8 e) = 256 blocks = 1/CU. 64 flat K-tiles (4 ct x 16 kt),
// epilogue every 16. b1/wts staged to LDS once.
__global__ __launch_bounds__(512, 1) void ffn_stage1_f(
    const bf16* __restrict__ xb, const bf16* __restrict__ w1t,
    const float* __restrict__ b1, const float* __restrict__ wts,
    bf16* __restrict__ G) {
  __shared__ __align__(16) char lds[98304];
  __shared__ float b1s[1024];
  __shared__ float wls[256];
  const int mt = blockIdx.x, e = blockIdx.y;
  PIPE_DECLS
  b1s[t] = b1[e * Hh + t];
  b1s[512 + t] = b1[e * Hh + 512 + t];
  if (t < 256) wls[t] = wts[((size_t)mt * 256 + t) * Ee + e];

  const bf16* Ag = xb + (size_t)mt * 256 * Dd;
  const bf16* Bg0 = w1t + (size_t)e * Hh * Dd;

  auto stageA = [&](int it, char* buf) {
    const int k0 = (it & 15) * 32;
    gload_lds16(Ag + (size_t)srow * Dd + k0 + sq * 8, buf + wid * 1024);
    gload_lds16(Ag + (size_t)(128 + srow) * Dd + k0 + sq * 8, buf + 8192 + wid * 1024);
  };
  auto stageB = [&](int it, char* buf) {
    const bf16* Bg = Bg0 + (size_t)(it >> 4) * 256 * Dd;
    const int k0 = (it & 15) * 32;
    gload_lds16(Bg + (size_t)srow * Dd + k0 + sq * 8, buf + 16384 + wid * 1024);
    gload_lds16(Bg + (size_t)(128 + srow) * Dd + k0 + sq * 8, buf + 24576 + wid * 1024);
  };

  f32x4 acc[8][4] = {};
  const int NT = 64;
  stageA(0, lds); stageB(0, lds);
  stageA(1, lds + 32768); stageB(1, lds + 32768);
  for (int it = 0; it < NT; ++it) {
    char* buf = lds + (it % 3) * 32768;
    char* nbuf = lds + ((it + 2) % 3) * 32768;
    if (it + 1 < NT) {
      asm volatile("s_waitcnt vmcnt(4)" ::: "memory");
    } else {
      asm volatile("s_waitcnt vmcnt(0)" ::: "memory");
    }
    __builtin_amdgcn_s_barrier();
    {
      PHASE0(buf)
      if (it + 2 < NT) stageA(it + 2, nbuf);
      MFMA_CLUSTER(af, 0)
      PHASE1_READS(buf)
      if (it + 2 < NT) stageB(it + 2, nbuf);
      MFMA_CLUSTER(af2, 4)
    }
    if ((it & 15) == 15) {
      const int ct = it >> 4;
      float b1v[4][4];
#pragma unroll
      for (int fj = 0; fj < 4; ++fj)
#pragma unroll
        for (int r = 0; r < 4; ++r)
          b1v[fj][r] = b1s[ct * 256 + wn * 64 + fj * 16 + fq * 4 + r];
#pragma unroll
      for (int fi = 0; fi < 8; ++fi) {
        const int m = mt * 256 + wm * 128 + fi * 16 + fr;
        const float wgt = wls[wm * 128 + fi * 16 + fr];
        bf16* gp = G + (size_t)m * GKS + e * Hh + ct * 256 + wn * 64 + fq * 4;
#pragma unroll
        for (int fj = 0; fj < 4; ++fj) {
          bf16x4 o;
#pragma unroll
          for (int r = 0; r < 4; ++r) {
            float v = acc[fi][fj][r] + b1v[fj][r];
            o[r] = (bf16)(gelu_fast(v) * wgt);
          }
          *(bf16x4*)(gp + fj * 16) = o;
#pragma unroll
          for (int r = 0; r < 4; ++r) acc[fi][fj][r] = 0.f;
        }
      }
    }
  }
}

// ---------------- stage 2: split-K partial, fine-interleaved ----------------
// Grid (32 mt, 2 nt, 4 s) = 256 blocks = 1/CU, 64 K-tiles each.
__global__ __launch_bounds__(512, 1) void ffn_stage2_f(
    const bf16* __restrict__ G, const bf16* __restrict__ w2t,
    float* __restrict__ P) {
  __shared__ __align__(16) char lds[98304];
  const int mt = blockIdx.x, nt = blockIdx.y, s = blockIdx.z;
  PIPE_DECLS
  const bf16* Ag = G + (size_t)mt * 256 * GKS + (size_t)s * 2048;
  const bf16* Bg = w2t + (size_t)nt * 256 * GKS + (size_t)s * 2048;

  auto stageA = [&](int it, char* buf) {
    const int k0 = it * 32;
    gload_lds16(Ag + (size_t)srow * GKS + k0 + sq * 8, buf + wid * 1024);
    gload_lds16(Ag + (size_t)(128 + srow) * GKS + k0 + sq * 8, buf + 8192 + wid * 1024);
  };
  auto stageB = [&](int it, char* buf) {
    const int k0 = it * 32;
    gload_lds16(Bg + (size_t)srow * GKS + k0 + sq * 8, buf + 16384 + wid * 1024);
    gload_lds16(Bg + (size_t)(128 + srow) * GKS + k0 + sq * 8, buf + 24576 + wid * 1024);
  };

  f32x4 acc[8][4] = {};
  const int NT = 64;
  stageA(0, lds); stageB(0, lds);
  stageA(1, lds + 32768); stageB(1, lds + 32768);
  for (int it = 0; it < NT; ++it) {
    char* buf = lds + (it % 3) * 32768;
    char* nbuf = lds + ((it + 2) % 3) * 32768;
    if (it + 1 < NT) {
      asm volatile("s_waitcnt vmcnt(4)" ::: "memory");
    } else {
      asm volatile("s_waitcnt vmcnt(0)" ::: "memory");
    }
    __builtin_amdgcn_s_barrier();
    {
      PHASE0(buf)
      if (it + 2 < NT) stageA(it + 2, nbuf);
      MFMA_CLUSTER(af, 0)
      PHASE1_READS(buf)
      if (it + 2 < NT) stageB(it + 2, nbuf);
      MFMA_CLUSTER(af2, 4)
    }
  }

  float* Pp = P + (size_t)s * Mm * Dd;
#pragma unroll
  for (int fi = 0; fi < 8; ++fi) {
    const size_t m = (size_t)mt * 256 + wm * 128 + fi * 16 + fr;
    float* pp = Pp + m * Dd + nt * 256 + wn * 64 + fq * 4;
#pragma unroll
    for (int fj = 0; fj < 4; ++fj) *(f32x4*)(pp + fj * 16) = acc[fi][fj];
  }
}

// ---------------- reduce partials + bias ------------------------------------
__global__ __launch_bounds__(256) void reduce_bias(
    const float* __restrict__ P, const float* __restrict__ wts,
    const float* __restrict__ b2, float* __restrict__ out, int S) {
  const int n4 = Mm * Dd / 4;
  int i = blockIdx.x * 256 + threadIdx.x;
  if (i >= n4) return;
  const int m = i / (Dd / 4);
  const int d0 = (i % (Dd / 4)) * 4;
  float4 a = ((const float4*)P)[i];
  for (int s = 1; s < S; ++s) {
    float4 p = ((const float4*)P)[(size_t)s * n4 + i];
    a.x += p.x; a.y += p.y; a.z += p.z; a.w += p.w;
  }
  const float* wr = wts + (size_t)m * Ee;
#pragma unroll
  for (int e = 0; e < Ee; ++e) {
    const float w = wr[e];
    float4 b = *(const float4*)(b2 + e * Dd + d0);
    a.x += w * b.x; a.y += w * b.y; a.z += w * b.z; a.w += w * b.w;
  }
  ((float4*)out)[i] = a;
}

// ============ fallback: 128^2 m97-structure path (R3 proven) ================
template <int ARS, int BRS>
DEV void gemm_core(const bf16* __restrict__ Ag, const bf16* __restrict__ Bg,
                   int ksteps, f32x4 (&acc)[4][4], bf16* As, bf16* Bs) {
  const int t = threadIdx.x;
  const int lane = t & 63;
  const int w = t >> 6;
  const int srow = t >> 3;
  const int sseg = t & 7;
  const int wr = w >> 1, wc = w & 1;
  const int fr = lane & 15;
  const int fg = lane >> 4;
  for (int s = 0; s < ksteps; ++s) {
    __syncthreads();
#pragma unroll
    for (int i = 0; i < 4; ++i) {
      const int row = i * 32 + srow;
      const int q = sseg ^ (row & 7);
      gload_lds16(Ag + (size_t)row * ARS + s * 64 + q * 8,
                  (char*)As + i * 4096 + w * 1024);
      gload_lds16(Bg + (size_t)row * BRS + s * 64 + q * 8,
                  (char*)Bs + i * 4096 + w * 1024);
    }
    __syncthreads();
#pragma unroll
    for (int kk = 0; kk < 2; ++kk) {
      bf16x8 af[4], bfr[4];
#pragma unroll
      for (int mi = 0; mi < 4; ++mi) {
        const int row = wr * 64 + mi * 16 + fr;
        const int q = (kk * 4 + fg) ^ (row & 7);
        af[mi] = *(const bf16x8*)((const char*)As + row * 128 + q * 16);
      }
#pragma unroll
      for (int ni = 0; ni < 4; ++ni) {
        const int row = wc * 64 + ni * 16 + fr;
        const int q = (kk * 4 + fg) ^ (row & 7);
        bfr[ni] = *(const bf16x8*)((const char*)Bs + row * 128 + q * 16);
      }
#pragma unroll
      for (int mi = 0; mi < 4; ++mi)
#pragma unroll
        for (int ni = 0; ni < 4; ++ni)
          acc[mi][ni] = __builtin_amdgcn_mfma_f32_16x16x32_bf16(
              af[mi], bfr[ni], acc[mi][ni], 0, 0, 0);
    }
  }
}

__global__ __launch_bounds__(256) void ffn_stage1_t(
    const bf16* __restrict__ xb, const bf16* __restrict__ w1t,
    const float* __restrict__ b1, const float* __restrict__ wts,
    bf16* __restrict__ G) {
  __shared__ __align__(16) bf16 As[128 * 64];
  __shared__ __align__(16) bf16 Bs[128 * 64];
  __shared__ float b1s[128];
  __shared__ float wls[128];
  const int mt = blockIdx.x, ht = blockIdx.y, e = blockIdx.z;
  const int t = threadIdx.x;
  if (t < 128) b1s[t] = b1[e * Hh + ht * 128 + t];
  else wls[t - 128] = wts[((size_t)mt * 128 + (t - 128)) * Ee + e];
  f32x4 acc[4][4] = {};
  const bf16* Ag = xb + (size_t)mt * 128 * Dd;
  const bf16* Bg = w1t + ((size_t)e * Hh + (size_t)ht * 128) * Dd;
  gemm_core<Dd, Dd>(Ag, Bg, Dd / 64, acc, As, Bs);
  const int lane = t & 63, w = t >> 6;
  const int wr = w >> 1, wc = w & 1, fr = lane & 15, fq = lane >> 4;
  float bcol[4];
#pragma unroll
  for (int ni = 0; ni < 4; ++ni) bcol[ni] = b1s[wc * 64 + ni * 16 + fr];
  bf16* gp = G + ((size_t)mt * 128 + wr * 64 + fq * 4) * GKS
               + (size_t)e * Hh + ht * 128 + wc * 64 + fr;
#pragma unroll
  for (int mi = 0; mi < 4; ++mi)
#pragma unroll
    for (int r = 0; r < 4; ++r) {
      const float wgt = wls[wr * 64 + mi * 16 + fq * 4 + r];
#pragma unroll
      for (int ni = 0; ni < 4; ++ni) {
        float v = acc[mi][ni][r] + bcol[ni];
        gp[(size_t)(mi * 16 + r) * GKS + ni * 16] = (bf16)(gelu_fast(v) * wgt);
      }
    }
}

__global__ __launch_bounds__(256) void ffn_stage2_partial(
    const bf16* __restrict__ G, const bf16* __restrict__ w2t,
    float* __restrict__ P, int kchunk) {
  __shared__ __align__(16) bf16 As[128 * 64];
  __shared__ __align__(16) bf16 Bs[128 * 64];
  const int mt = blockIdx.x, nt = blockIdx.y, s = blockIdx.z;
  f32x4 acc[4][4] = {};
  const bf16* Ag = G + (size_t)mt * 128 * GKS + (size_t)s * kchunk;
  const bf16* Bg = w2t + (size_t)nt * 128 * GKS + (size_t)s * kchunk;
  gemm_core<GKS, GKS>(Ag, Bg, kchunk / 64, acc, As, Bs);
  float* Pp = P + (size_t)s * Mm * Dd;
  const int t = threadIdx.x;
  const int lane = t & 63, w = t >> 6;
  const int wr = w >> 1, wc = w & 1, fr = lane & 15, fq = lane >> 4;
#pragma unroll
  for (int mi = 0; mi < 4; ++mi)
#pragma unroll
    for (int r = 0; r < 4; ++r) {
      const size_t m = (size_t)mt * 128 + wr * 64 + mi * 16 + fq * 4 + r;
#pragma unroll
      for (int ni = 0; ni < 4; ++ni) {
        const int d = nt * 128 + wc * 64 + ni * 16 + fr;
        Pp[m * Dd + d] = acc[mi][ni][r];
      }
    }
}

// ---------------- launch ----------------------------------------------------
extern "C" void kernel_launch(void* const* d_in, const int* in_sizes, int n_in,
                              void* d_out, int out_size, void* d_ws, size_t ws_size,
                              hipStream_t stream) {
  const float* x   = (const float*)d_in[0];
  const float* wts = (const float*)d_in[1];
  const float* w1  = (const float*)d_in[2];
  const float* b1  = (const float*)d_in[3];
  const float* w2  = (const float*)d_in[4];
  const float* b2  = (const float*)d_in[5];
  float* out = (float*)d_out;

  char* ws = (char*)d_ws;
  size_t off = 0;
  bf16* xb  = (bf16*)(ws + off); off += (size_t)Mm * Dd * 2;
  bf16* w1t = (bf16*)(ws + off); off += (size_t)Ee * Hh * Dd * 2;
  bf16* w2t = (bf16*)(ws + off); off += (size_t)Dd * Ee * Hh * 2;

  const size_t gfull = (size_t)Mm * Ee * Hh * 2;  // 134 MB
  const size_t psz   = (size_t)Mm * Dd * 4;       // 16.8 MB

  cvt_x_kernel<<<(Mm * Dd / 4 + 255) / 256, 256, 0, stream>>>(x, xb, Mm * Dd / 4);
  transpose_cvt<<<dim3(Hh / 64, Dd / 64, Ee), 256, 0, stream>>>(
      w1, w1t, Dd, Hh, (size_t)Dd * Hh, (size_t)Hh * Dd, Dd);
  transpose_cvt<<<dim3(Dd / 64, Hh / 64, Ee), 256, 0, stream>>>(
      w2, w2t, Hh, Dd, (size_t)Hh * Dd, (size_t)Hh, Ee * Hh);

  if (ws_size >= off + gfull + 4 * psz) {
    // main path: 256^2 BK=32 fine-interleaved triple-buffer, split-K S=4
    bf16* G = (bf16*)(ws + off);
    float* P = (float*)(ws + off + gfull);
    ffn_stage1_f<<<dim3(Mm / 256, Ee), 512, 0, stream>>>(
        xb, w1t, b1, wts, G);
    ffn_stage2_f<<<dim3(Mm / 256, Dd / 256, 4), 512, 0, stream>>>(
        G, w2t, P);
    reduce_bias<<<(Mm * Dd / 4 + 255) / 256, 256, 0, stream>>>(P, wts, b2, out, 4);
  } else if (ws_size >= off + gfull + 2 * psz) {
    // fallback: 128^2 split-K S=2 (R3 proven)
    bf16* G = (bf16*)(ws + off);
    float* P = (float*)(ws + off + gfull);
    ffn_stage1_t<<<dim3(Mm / 128, Hh / 128, Ee), 256, 0, stream>>>(
        xb, w1t, b1, wts, G);
    ffn_stage2_partial<<<dim3(Mm / 128, Dd / 128, 2), 256, 0, stream>>>(
        G, w2t, P, GKS / 2);
    reduce_bias<<<(Mm * Dd / 4 + 255) / 256, 256, 0, stream>>>(P, wts, b2, out, 2);
  }
}